// Round 1
// baseline (399.745 us; speedup 1.0000x reference)
//
#include <hip/hip_runtime.h>
#include <stdint.h>

// ---------------------------------------------------------------------------
// Bucketed linear attention, MI355X round 0 (correctness-first MFMA pipeline)
//   ws layout (243.3 MB total):
//     xb   bf16 x            33,554,432 B @ 0
//     wq   bf16 qkv_w         6,291,456 B @ 33554432
//     wp   bf16 proj_w        2,097,152 B @ 39845888
//     qkv  bf16 [16384][3072] 100,663,296 B @ 41943040   (reused as AT later)
//     Qf   bf16 [bh][u][n][e] 33,554,432 B @ 142606336
//     Kt   bf16 [bh][u][e][n] 33,554,432 B @ 176160768
//     Vt   bf16 [bh][u][e][n] 33,554,432 B @ 209715200
// ---------------------------------------------------------------------------

typedef unsigned short u16;
typedef u16   u16x4  __attribute__((ext_vector_type(4)));
typedef u16   u16x8  __attribute__((ext_vector_type(8)));
typedef float f32x4  __attribute__((ext_vector_type(4)));
typedef float float4v __attribute__((ext_vector_type(4)));
typedef __bf16 bf16x8 __attribute__((ext_vector_type(8)));

__device__ __forceinline__ u16 f2bf(float f) {
  return __builtin_bit_cast(u16, (__bf16)f);
}
__device__ __forceinline__ float bf2f(u16 h) {
  return (float)__builtin_bit_cast(__bf16, h);
}

// --------------------------- fp32 -> bf16 convert ---------------------------
__global__ __launch_bounds__(256) void cvt_f32_to_bf16(
    const float* __restrict__ in, u16* __restrict__ out, int n4) {
  int i = blockIdx.x * 256 + threadIdx.x;
  if (i >= n4) return;
  float4v v = reinterpret_cast<const float4v*>(in)[i];
  u16x4 o;
  o.x = f2bf(v.x); o.y = f2bf(v.y); o.z = f2bf(v.z); o.w = f2bf(v.w);
  reinterpret_cast<u16x4*>(out)[i] = o;
}

// --------------------------- NT bf16 MFMA GEMM ------------------------------
// C[M][N] = A[M][K] @ B[N][K]^T  (+bias when fp32 out). 128x128 tile, BK=64,
// 4 waves (2x2), 64x64 per wave, 16x16x32 bf16 MFMA, XOR-swizzled LDS
// (byte ^= (row&7)<<4) on both write and read sides (reg-staged).
template <bool BF16_OUT>
__global__ __launch_bounds__(256, 2) void gemm_bt(
    const u16* __restrict__ A,     // [M][K] bf16
    const u16* __restrict__ B,     // [N][K] bf16
    const float* __restrict__ bias,// [N] (used when !BF16_OUT)
    void* __restrict__ Cv,
    int M, int N, int K) {
  __shared__ u16 As[128 * 64];
  __shared__ u16 Bs[128 * 64];
  const int tid  = threadIdx.x;
  const int lane = tid & 63;
  const int wave = tid >> 6;
  const int wm = wave >> 1, wn = wave & 1;
  const int l15 = lane & 15, l4 = lane >> 4;
  const int ntn = N >> 7;
  const int bm = blockIdx.x / ntn, bn = blockIdx.x % ntn;

  f32x4 acc[4][4] = {};

  const u16* Ab = A + (size_t)(bm * 128) * K;
  const u16* Bb = B + (size_t)(bn * 128) * K;
  const int crow = tid >> 3;  // 0..31
  const int ccol = tid & 7;   // 0..7 (16B chunk within 128B row)

  for (int kt = 0; kt < K; kt += 64) {
    u16x8 ra[4], rb[4];
#pragma unroll
    for (int j = 0; j < 4; ++j) {
      int row = crow + 32 * j;
      ra[j] = *reinterpret_cast<const u16x8*>(Ab + (size_t)row * K + kt + ccol * 8);
      rb[j] = *reinterpret_cast<const u16x8*>(Bb + (size_t)row * K + kt + ccol * 8);
    }
    __syncthreads();  // prior iteration's LDS reads done
#pragma unroll
    for (int j = 0; j < 4; ++j) {
      int row = crow + 32 * j;
      int off = row * 128 + ((ccol * 16) ^ ((row & 7) << 4));
      *reinterpret_cast<u16x8*>(reinterpret_cast<char*>(As) + off) = ra[j];
      *reinterpret_cast<u16x8*>(reinterpret_cast<char*>(Bs) + off) = rb[j];
    }
    __syncthreads();
#pragma unroll
    for (int kk = 0; kk < 2; ++kk) {
      const int cb = kk * 64 + l4 * 16;
      bf16x8 af[4], bfr[4];
#pragma unroll
      for (int mi = 0; mi < 4; ++mi) {
        int row = wm * 64 + mi * 16 + l15;
        af[mi] = *reinterpret_cast<const bf16x8*>(
            reinterpret_cast<const char*>(As) + row * 128 + (cb ^ ((row & 7) << 4)));
      }
#pragma unroll
      for (int ni = 0; ni < 4; ++ni) {
        int row = wn * 64 + ni * 16 + l15;
        bfr[ni] = *reinterpret_cast<const bf16x8*>(
            reinterpret_cast<const char*>(Bs) + row * 128 + (cb ^ ((row & 7) << 4)));
      }
#pragma unroll
      for (int mi = 0; mi < 4; ++mi)
#pragma unroll
        for (int ni = 0; ni < 4; ++ni)
          acc[mi][ni] = __builtin_amdgcn_mfma_f32_16x16x32_bf16(
              af[mi], bfr[ni], acc[mi][ni], 0, 0, 0);
    }
  }

  // epilogue: D row=(lane>>4)*4+reg, col=lane&15 (m89-verified)
  const int row0 = bm * 128 + wm * 64 + l4 * 4;
  const int col0 = bn * 128 + wn * 64 + l15;
  if constexpr (BF16_OUT) {
    u16* C = (u16*)Cv;
#pragma unroll
    for (int mi = 0; mi < 4; ++mi)
#pragma unroll
      for (int i = 0; i < 4; ++i) {
        size_t r = (size_t)(row0 + mi * 16 + i) * N;
#pragma unroll
        for (int ni = 0; ni < 4; ++ni)
          C[r + col0 + ni * 16] = f2bf(acc[mi][ni][i]);
      }
  } else {
    float* C = (float*)Cv;
    float bv[4];
#pragma unroll
    for (int ni = 0; ni < 4; ++ni) bv[ni] = bias[col0 + ni * 16];
#pragma unroll
    for (int mi = 0; mi < 4; ++mi)
#pragma unroll
      for (int i = 0; i < 4; ++i) {
        size_t r = (size_t)(row0 + mi * 16 + i) * N;
#pragma unroll
        for (int ni = 0; ni < 4; ++ni)
          C[r + col0 + ni * 16] = acc[mi][ni][i] + bv[ni];
      }
  }
}

// ----------------------- feature maps + bucket layout -----------------------
// One block per (b,h,u) bucket. Q: row softmax(e)*e^-0.5 -> Qf[bh][u][n][e].
// K: exp -> transposed Kt[bh][u][e][n].  V: transposed Vt[bh][u][e][n].
__global__ __launch_bounds__(256) void featuremap(
    const u16* __restrict__ qkv,  // [16384][3072] bf16
    u16* __restrict__ Q, u16* __restrict__ Kt, u16* __restrict__ Vt) {
  const int bid = blockIdx.x;
  const int u = bid & 63;
  const int bh = bid >> 6;
  const int b = bh >> 4, h = bh & 15;
  const int tid = threadIdx.x, lane = tid & 63, wave = tid >> 6;
  __shared__ float ts[64][65];

  const size_t mrow  = (size_t)b * 4096 + u * 64;
  const size_t obase = ((size_t)bh * 64 + u) * 4096;

  // Q: softmax over e (64 lanes = 64 e), wave handles 16 rows
#pragma unroll 1
  for (int r = 0; r < 16; ++r) {
    int n = wave * 16 + r;
    float v = bf2f(qkv[(mrow + n) * 3072 + h * 64 + lane]);
    float mx = v;
#pragma unroll
    for (int o = 32; o; o >>= 1) mx = fmaxf(mx, __shfl_xor(mx, o));
    float ex = __expf(v - mx);
    float sm = ex;
#pragma unroll
    for (int o = 32; o; o >>= 1) sm += __shfl_xor(sm, o);
    Q[obase + n * 64 + lane] = f2bf(ex / sm * 0.125f);  // e^-0.5 = 1/8
  }

  // K: exp + LDS transpose
  {
    int n = tid >> 2, c = tid & 3;
    const u16* kp = qkv + (mrow + n) * 3072 + 1024 + h * 64 + c * 16;
#pragma unroll
    for (int j = 0; j < 16; ++j) ts[n][c * 16 + j] = __expf(bf2f(kp[j]));
  }
  __syncthreads();
  {
    int e = tid >> 2, c = tid & 3;
    u16x8 o0, o1;
#pragma unroll
    for (int j = 0; j < 8; ++j) o0[j] = f2bf(ts[c * 16 + j][e]);
#pragma unroll
    for (int j = 0; j < 8; ++j) o1[j] = f2bf(ts[c * 16 + 8 + j][e]);
    u16* op = Kt + obase + e * 64 + c * 16;
    *reinterpret_cast<u16x8*>(op) = o0;
    *reinterpret_cast<u16x8*>(op + 8) = o1;
  }
  __syncthreads();
  // V: LDS transpose
  {
    int n = tid >> 2, c = tid & 3;
    const u16* vp = qkv + (mrow + n) * 3072 + 2048 + h * 64 + c * 16;
#pragma unroll
    for (int j = 0; j < 16; ++j) ts[n][c * 16 + j] = bf2f(vp[j]);
  }
  __syncthreads();
  {
    int e = tid >> 2, c = tid & 3;
    u16x8 o0, o1;
#pragma unroll
    for (int j = 0; j < 8; ++j) o0[j] = f2bf(ts[c * 16 + j][e]);
#pragma unroll
    for (int j = 0; j < 8; ++j) o1[j] = f2bf(ts[c * 16 + 8 + j][e]);
    u16* op = Vt + obase + e * 64 + c * 16;
    *reinterpret_cast<u16x8*>(op) = o0;
    *reinterpret_cast<u16x8*>(op + 8) = o1;
  }
}

// ------------------------- bucketed scan (middle) ---------------------------
// One block per (b,h, s=e-column-half). Sequential over u=0..63 keeping
// ctT[e][d] = context^T and kcum[d] in fp32 LDS (exclusive cumsums).
__global__ __launch_bounds__(256) void middle(
    const u16* __restrict__ Q,   // [bh][u][n][e]
    const u16* __restrict__ Kt,  // [bh][u][d][n]
    const u16* __restrict__ Vt,  // [bh][u][e][n]
    u16* __restrict__ AT) {      // [16384][1024] bf16
  const int bid = blockIdx.x;
  const int bh = bid >> 1, s = bid & 1;
  const int b = bh >> 4, h = bh & 15;
  const int tid = threadIdx.x, lane = tid & 63, wave = tid >> 6;
  const int l15 = lane & 15, l4 = lane >> 4;

  __shared__ float ctT[32][68];  // ctT[e - s*32][d], pad 68 for banks
  __shared__ float kcum[64];
  __shared__ float dpart[64][4];
  __shared__ float dinv[64];

  for (int i = tid; i < 32 * 68; i += 256) (&ctT[0][0])[i] = 0.f;
  if (tid < 64) kcum[tid] = 0.f;
  __syncthreads();

  const size_t base = (size_t)bh * (64 * 64 * 64);
  const int nq = tid & 63, cq = tid >> 6;

  for (int u = 0; u < 64; ++u) {
    const u16* Qu = Q  + base + u * 4096;
    const u16* Ku = Kt + base + u * 4096;
    const u16* Vu = Vt + base + u * 4096;

    // Phase A: D partials: dot(q[n], kcum) (kcum is exclusive: buckets < u)
    {
      const u16* qp = Qu + nq * 64 + cq * 16;
      float a = 0.f;
#pragma unroll
      for (int j = 0; j < 16; ++j) a += bf2f(qp[j]) * kcum[cq * 16 + j];
      dpart[nq][cq] = a;
    }
    __syncthreads();
    if (tid < 64) {
      float d = dpart[tid][0] + dpart[tid][1] + dpart[tid][2] + dpart[tid][3];
      dinv[tid] = 1.f / fmaxf(d, 1e-3f);
    }
    __syncthreads();

    // Phase B: attn = (q @ context) * D_inv ; write AT
    {
      f32x4 acc[2] = {};
#pragma unroll
      for (int kk = 0; kk < 2; ++kk) {
        bf16x8 aq = *reinterpret_cast<const bf16x8*>(
            Qu + (wave * 16 + l15) * 64 + kk * 32 + l4 * 8);
#pragma unroll
        for (int ni = 0; ni < 2; ++ni) {
          const float* cp = &ctT[ni * 16 + l15][kk * 32 + l4 * 8];
          bf16x8 bv;
#pragma unroll
          for (int j = 0; j < 8; ++j) bv[j] = (__bf16)cp[j];
          acc[ni] = __builtin_amdgcn_mfma_f32_16x16x32_bf16(aq, bv, acc[ni], 0, 0, 0);
        }
      }
      const size_t orow = ((size_t)b * 4096 + u * 64 + wave * 16 + l4 * 4) * 1024
                          + h * 64 + s * 32 + l15;
#pragma unroll
      for (int i = 0; i < 4; ++i) {
        float di = dinv[wave * 16 + l4 * 4 + i];
#pragma unroll
        for (int ni = 0; ni < 2; ++ni)
          AT[orow + (size_t)i * 1024 + ni * 16] = f2bf(acc[ni][i] * di);
      }
    }
    __syncthreads();

    // Phase C: context^T += (K^T V)^T slice ; kcum partials
    {
      f32x4 accu[2] = {};
#pragma unroll
      for (int kk = 0; kk < 2; ++kk) {
        bf16x8 ak = *reinterpret_cast<const bf16x8*>(
            Ku + (wave * 16 + l15) * 64 + kk * 32 + l4 * 8);
#pragma unroll
        for (int ni = 0; ni < 2; ++ni) {
          bf16x8 bv = *reinterpret_cast<const bf16x8*>(
              Vu + (s * 32 + ni * 16 + l15) * 64 + kk * 32 + l4 * 8);
          accu[ni] = __builtin_amdgcn_mfma_f32_16x16x32_bf16(ak, bv, accu[ni], 0, 0, 0);
        }
      }
#pragma unroll
      for (int ni = 0; ni < 2; ++ni)
#pragma unroll
        for (int i = 0; i < 4; ++i)
          ctT[ni * 16 + l15][wave * 16 + l4 * 4 + i] += accu[ni][i];
      const u16* kp = Ku + nq * 64 + cq * 16;
      float a = 0.f;
#pragma unroll
      for (int j = 0; j < 16; ++j) a += bf2f(kp[j]);
      dpart[nq][cq] = a;
    }
    __syncthreads();
    if (tid < 64)
      kcum[tid] += dpart[tid][0] + dpart[tid][1] + dpart[tid][2] + dpart[tid][3];
    __syncthreads();
  }
}

// ----------------------------------------------------------------------------
extern "C" void kernel_launch(void* const* d_in, const int* in_sizes, int n_in,
                              void* d_out, int out_size, void* d_ws, size_t ws_size,
                              hipStream_t stream) {
  (void)in_sizes; (void)n_in; (void)out_size; (void)ws_size;
  const float* x      = (const float*)d_in[0];
  const float* qkv_w  = (const float*)d_in[1];
  const float* proj_w = (const float*)d_in[2];
  const float* proj_b = (const float*)d_in[3];
  float* out = (float*)d_out;

  char* ws = (char*)d_ws;
  u16* xb  = (u16*)(ws);
  u16* wq  = (u16*)(ws + 33554432);
  u16* wp  = (u16*)(ws + 39845888);
  u16* qkv = (u16*)(ws + 41943040);
  u16* Qf  = (u16*)(ws + 142606336);
  u16* Kt  = (u16*)(ws + 176160768);
  u16* Vt  = (u16*)(ws + 209715200);
  u16* AT  = qkv;  // qkv region is dead after featuremap

  cvt_f32_to_bf16<<<dim3(16384), dim3(256), 0, stream>>>(x, xb, 16777216 / 4);
  cvt_f32_to_bf16<<<dim3(3072),  dim3(256), 0, stream>>>(qkv_w, wq, 3145728 / 4);
  cvt_f32_to_bf16<<<dim3(1024),  dim3(256), 0, stream>>>(proj_w, wp, 1048576 / 4);

  gemm_bt<true ><<<dim3(128 * 24), dim3(256), 0, stream>>>(xb, wq, nullptr, qkv,
                                                           16384, 3072, 1024);
  featuremap<<<dim3(4096), dim3(256), 0, stream>>>(qkv, Qf, Kt, Vt);
  middle<<<dim3(128), dim3(256), 0, stream>>>(Qf, Kt, Vt, AT);
  gemm_bt<false><<<dim3(128 * 8), dim3(256), 0, stream>>>(AT, wp, proj_b, out,
                                                          16384, 1024, 1024);
}

// Round 2
// 291.567 us; speedup vs baseline: 1.3710x; 1.3710x over previous
//
#include <hip/hip_runtime.h>
#include <stdint.h>

// ---------------------------------------------------------------------------
// Bucketed linear attention, round 1: parallelize the bucket scan.
//   ws layout (<= 211 MB):
//     xb   bf16 x            33,554,432 B @ 0
//     wq   bf16 qkv_w         6,291,456 B @ 33554432
//     wp   bf16 proj_w        2,097,152 B @ 39845888
//     qkv  bf16 [16384][3072] 100,663,296 B @ 41943040   (reused as AT later)
//     Qf   bf16 [bh*64+u][n][e] 33,554,432 B @ 142606336
//     ctxb bf16 [bh*64+u][e][d] 33,554,432 B @ 176160768  (in-place excl scan)
//     ksum f32  [bh*64+u][d]     1,048,576 B @ 209715200  (in-place excl scan)
// ---------------------------------------------------------------------------

typedef unsigned short u16;
typedef u16   u16x4  __attribute__((ext_vector_type(4)));
typedef u16   u16x8  __attribute__((ext_vector_type(8)));
typedef float f32x4  __attribute__((ext_vector_type(4)));
typedef float float4v __attribute__((ext_vector_type(4)));
typedef __bf16 bf16x8 __attribute__((ext_vector_type(8)));

__device__ __forceinline__ u16 f2bf(float f) {
  return __builtin_bit_cast(u16, (__bf16)f);
}
__device__ __forceinline__ float bf2f(u16 h) {
  return (float)__builtin_bit_cast(__bf16, h);
}

// --------------------------- fp32 -> bf16 convert ---------------------------
__global__ __launch_bounds__(256) void cvt_f32_to_bf16(
    const float* __restrict__ in, u16* __restrict__ out, int n4) {
  int i = blockIdx.x * 256 + threadIdx.x;
  if (i >= n4) return;
  float4v v = reinterpret_cast<const float4v*>(in)[i];
  u16x4 o;
  o.x = f2bf(v.x); o.y = f2bf(v.y); o.z = f2bf(v.z); o.w = f2bf(v.w);
  reinterpret_cast<u16x4*>(out)[i] = o;
}

// --------------------------- NT bf16 MFMA GEMM ------------------------------
// C[M][N] = A[M][K] @ B[N][K]^T  (+bias when fp32 out). 128x128 tile, BK=64,
// 4 waves (2x2), XOR-swizzled LDS, XCD-aware block swizzle (grid%8==0).
template <bool BF16_OUT>
__global__ __launch_bounds__(256, 2) void gemm_bt(
    const u16* __restrict__ A,     // [M][K] bf16
    const u16* __restrict__ B,     // [N][K] bf16
    const float* __restrict__ bias,// [N] (used when !BF16_OUT)
    void* __restrict__ Cv,
    int M, int N, int K) {
  __shared__ u16 As[128 * 64];
  __shared__ u16 Bs[128 * 64];
  const int tid  = threadIdx.x;
  const int lane = tid & 63;
  const int wave = tid >> 6;
  const int wm = wave >> 1, wn = wave & 1;
  const int l15 = lane & 15, l4 = lane >> 4;
  const int ntn = N >> 7;
  // XCD-aware bijective swizzle (grid is a multiple of 8)
  const int cpx = gridDim.x >> 3;
  const int bid = (blockIdx.x & 7) * cpx + (blockIdx.x >> 3);
  const int bm = bid / ntn, bn = bid % ntn;

  f32x4 acc[4][4] = {};

  const u16* Ab = A + (size_t)(bm * 128) * K;
  const u16* Bb = B + (size_t)(bn * 128) * K;
  const int crow = tid >> 3;  // 0..31
  const int ccol = tid & 7;   // 0..7 (16B chunk within 128B row)

  for (int kt = 0; kt < K; kt += 64) {
    u16x8 ra[4], rb[4];
#pragma unroll
    for (int j = 0; j < 4; ++j) {
      int row = crow + 32 * j;
      ra[j] = *reinterpret_cast<const u16x8*>(Ab + (size_t)row * K + kt + ccol * 8);
      rb[j] = *reinterpret_cast<const u16x8*>(Bb + (size_t)row * K + kt + ccol * 8);
    }
    __syncthreads();  // prior iteration's LDS reads done
#pragma unroll
    for (int j = 0; j < 4; ++j) {
      int row = crow + 32 * j;
      int off = row * 128 + ((ccol * 16) ^ ((row & 7) << 4));
      *reinterpret_cast<u16x8*>(reinterpret_cast<char*>(As) + off) = ra[j];
      *reinterpret_cast<u16x8*>(reinterpret_cast<char*>(Bs) + off) = rb[j];
    }
    __syncthreads();
#pragma unroll
    for (int kk = 0; kk < 2; ++kk) {
      const int cb = kk * 64 + l4 * 16;
      bf16x8 af[4], bfr[4];
#pragma unroll
      for (int mi = 0; mi < 4; ++mi) {
        int row = wm * 64 + mi * 16 + l15;
        af[mi] = *reinterpret_cast<const bf16x8*>(
            reinterpret_cast<const char*>(As) + row * 128 + (cb ^ ((row & 7) << 4)));
      }
#pragma unroll
      for (int ni = 0; ni < 4; ++ni) {
        int row = wn * 64 + ni * 16 + l15;
        bfr[ni] = *reinterpret_cast<const bf16x8*>(
            reinterpret_cast<const char*>(Bs) + row * 128 + (cb ^ ((row & 7) << 4)));
      }
#pragma unroll
      for (int mi = 0; mi < 4; ++mi)
#pragma unroll
        for (int ni = 0; ni < 4; ++ni)
          acc[mi][ni] = __builtin_amdgcn_mfma_f32_16x16x32_bf16(
              af[mi], bfr[ni], acc[mi][ni], 0, 0, 0);
    }
  }

  // epilogue: D row=(lane>>4)*4+reg, col=lane&15
  const int row0 = bm * 128 + wm * 64 + l4 * 4;
  const int col0 = bn * 128 + wn * 64 + l15;
  if constexpr (BF16_OUT) {
    u16* C = (u16*)Cv;
#pragma unroll
    for (int mi = 0; mi < 4; ++mi)
#pragma unroll
      for (int i = 0; i < 4; ++i) {
        size_t r = (size_t)(row0 + mi * 16 + i) * N;
#pragma unroll
        for (int ni = 0; ni < 4; ++ni)
          C[r + col0 + ni * 16] = f2bf(acc[mi][ni][i]);
      }
  } else {
    float* C = (float*)Cv;
    float bv[4];
#pragma unroll
    for (int ni = 0; ni < 4; ++ni) bv[ni] = bias[col0 + ni * 16];
#pragma unroll
    for (int mi = 0; mi < 4; ++mi)
#pragma unroll
      for (int i = 0; i < 4; ++i) {
        size_t r = (size_t)(row0 + mi * 16 + i) * N;
#pragma unroll
        for (int ni = 0; ni < 4; ++ni)
          C[r + col0 + ni * 16] = acc[mi][ni][i] + bv[ni];
      }
  }
}

// ------------------ feature maps + per-bucket K^T V (fused) -----------------
// One block per (b,h,u) bucket.
//   Qf[bkt][n][e]   = softmax_e(q) * e^-0.5              (bf16)
//   ctxb[bkt][e][d] = sum_n exp(k[n][d]) * v[n][e]       (bf16, per-bucket)
//   ksum[bkt][d]    = sum_n exp(k[n][d])                 (f32,  per-bucket)
__global__ __launch_bounds__(256) void featuremap_ctx(
    const u16* __restrict__ qkv,  // [16384][3072] bf16
    u16* __restrict__ Q, u16* __restrict__ ctxb, float* __restrict__ ksum) {
  const int bid = blockIdx.x;
  const int u = bid & 63;
  const int bh = bid >> 6;
  const int b = bh >> 4, h = bh & 15;
  const int tid = threadIdx.x, lane = tid & 63, wave = tid >> 6;
  const int l15 = lane & 15, l4 = lane >> 4;
  __shared__ float ts[64][65];
  __shared__ u16 KtL[64][72];  // [d][n], pad 72 (144B rows, 16B-aligned)
  __shared__ u16 VtL[64][72];  // [e][n]
  __shared__ float dp[64][4];

  const size_t mrow  = (size_t)b * 4096 + u * 64;
  const size_t obase = (size_t)bid * 4096;

  // --- Q: softmax over e (64 lanes = e), each wave 16 rows ---
#pragma unroll 1
  for (int r = 0; r < 16; ++r) {
    int n = wave * 16 + r;
    float v = bf2f(qkv[(mrow + n) * 3072 + h * 64 + lane]);
    float mx = v;
#pragma unroll
    for (int o = 32; o; o >>= 1) mx = fmaxf(mx, __shfl_xor(mx, o));
    float ex = __expf(v - mx);
    float sm = ex;
#pragma unroll
    for (int o = 32; o; o >>= 1) sm += __shfl_xor(sm, o);
    Q[obase + n * 64 + lane] = f2bf(ex / sm * 0.125f);  // e^-0.5 = 1/8
  }

  // --- K: exp + transpose into KtL ---
  {
    int n = tid >> 2, c = tid & 3;
    const u16* kp = qkv + (mrow + n) * 3072 + 1024 + h * 64 + c * 16;
#pragma unroll
    for (int j = 0; j < 16; ++j) ts[n][c * 16 + j] = __expf(bf2f(kp[j]));
  }
  __syncthreads();
  {
    int d = tid >> 2, c = tid & 3;
    u16x8 o0, o1;
#pragma unroll
    for (int j = 0; j < 8; ++j) o0[j] = f2bf(ts[c * 16 + j][d]);
#pragma unroll
    for (int j = 0; j < 8; ++j) o1[j] = f2bf(ts[c * 16 + 8 + j][d]);
    *reinterpret_cast<u16x8*>(&KtL[d][c * 16])     = o0;
    *reinterpret_cast<u16x8*>(&KtL[d][c * 16 + 8]) = o1;
  }
  __syncthreads();
  // ksum partials from KtL; V stage into ts (both safe after the sync)
  {
    int d = tid & 63, q = tid >> 6;
    float a = 0.f;
#pragma unroll
    for (int j = 0; j < 16; ++j) a += bf2f(KtL[d][q * 16 + j]);
    dp[d][q] = a;
  }
  {
    int n = tid >> 2, c = tid & 3;
    const u16* vp = qkv + (mrow + n) * 3072 + 2048 + h * 64 + c * 16;
#pragma unroll
    for (int j = 0; j < 16; ++j) ts[n][c * 16 + j] = bf2f(vp[j]);
  }
  __syncthreads();
  if (tid < 64)
    ksum[obase / 64 + tid] = dp[tid][0] + dp[tid][1] + dp[tid][2] + dp[tid][3];
  {
    int e = tid >> 2, c = tid & 3;
    u16x8 o0, o1;
#pragma unroll
    for (int j = 0; j < 8; ++j) o0[j] = f2bf(ts[c * 16 + j][e]);
#pragma unroll
    for (int j = 0; j < 8; ++j) o1[j] = f2bf(ts[c * 16 + 8 + j][e]);
    *reinterpret_cast<u16x8*>(&VtL[e][c * 16])     = o0;
    *reinterpret_cast<u16x8*>(&VtL[e][c * 16 + 8]) = o1;
  }
  __syncthreads();

  // --- ctxT[e][d] = sum_n VtL[e][n] * KtL[d][n]; wave -> 16 e-rows ---
  f32x4 acc[4] = {};
#pragma unroll
  for (int kk = 0; kk < 2; ++kk) {
    bf16x8 av = *reinterpret_cast<const bf16x8*>(&VtL[wave * 16 + l15][kk * 32 + l4 * 8]);
#pragma unroll
    for (int ni = 0; ni < 4; ++ni) {
      bf16x8 bk = *reinterpret_cast<const bf16x8*>(&KtL[ni * 16 + l15][kk * 32 + l4 * 8]);
      acc[ni] = __builtin_amdgcn_mfma_f32_16x16x32_bf16(av, bk, acc[ni], 0, 0, 0);
    }
  }
  u16* cb = ctxb + obase;
#pragma unroll
  for (int ni = 0; ni < 4; ++ni)
#pragma unroll
    for (int i = 0; i < 4; ++i)
      cb[(wave * 16 + l4 * 4 + i) * 64 + ni * 16 + l15] = f2bf(acc[ni][i]);
}

// -------------------- in-place exclusive cumsum over u ----------------------
// grid = 64 bh * 4 chunks. Each thread owns 4 bf16 of ctxT; chunk-0 wave-0
// also scans ksum. 4-deep named prefetch (loads independent of running sum).
__global__ __launch_bounds__(256) void scanctx(
    u16* __restrict__ ctxb, float* __restrict__ ksum) {
  const int bh = blockIdx.x >> 2, c = blockIdx.x & 3;
  const int tid = threadIdx.x;
  u16* p = ctxb + (size_t)bh * 64 * 4096 + c * 1024 + tid * 4;
  float* kp = ksum + (size_t)bh * 64 * 64 + tid;
  const bool dok = (c == 0) && (tid < 64);

  float r0 = 0.f, r1 = 0.f, r2 = 0.f, r3 = 0.f, runk = 0.f;
#define LC(i) (*reinterpret_cast<const u16x4*>(p + (size_t)(i) * 4096))
#define LK(i) (dok ? kp[(size_t)(i) * 64] : 0.f)
  u16x4 c0 = LC(0), c1 = LC(1), c2 = LC(2), c3 = LC(3);
  float k0 = LK(0), k1 = LK(1), k2 = LK(2), k3 = LK(3);
  for (int u = 0; u < 64; u += 4) {
    const int i4 = u + 4 < 64 ? u + 4 : 63, i5 = u + 5 < 64 ? u + 5 : 63;
    const int i6 = u + 6 < 64 ? u + 6 : 63, i7 = u + 7 < 64 ? u + 7 : 63;
    u16x4 n0 = LC(i4), n1 = LC(i5), n2 = LC(i6), n3 = LC(i7);
    float m0 = LK(i4), m1 = LK(i5), m2 = LK(i6), m3 = LK(i7);
#define STEP(idx, cv, kv)                                                  \
    {                                                                      \
      u16x4 o;                                                             \
      o.x = f2bf(r0); o.y = f2bf(r1); o.z = f2bf(r2); o.w = f2bf(r3);      \
      *reinterpret_cast<u16x4*>(p + (size_t)(idx) * 4096) = o;             \
      if (dok) kp[(size_t)(idx) * 64] = runk;                              \
      r0 += bf2f(cv.x); r1 += bf2f(cv.y); r2 += bf2f(cv.z);                \
      r3 += bf2f(cv.w); runk += kv;                                        \
    }
    STEP(u, c0, k0) STEP(u + 1, c1, k1) STEP(u + 2, c2, k2) STEP(u + 3, c3, k3)
#undef STEP
    c0 = n0; c1 = n1; c2 = n2; c3 = n3;
    k0 = m0; k1 = m1; k2 = m2; k3 = m3;
  }
#undef LC
#undef LK
}

// ---------------- apply: attn = (q @ ctx_excl) * Dinv -> AT -----------------
// One block per bucket. D[n] = q[n] . kcum_excl; 8 MFMAs per wave.
__global__ __launch_bounds__(256) void apply(
    const u16* __restrict__ Q, const u16* __restrict__ ctxc,
    const float* __restrict__ kcum, u16* __restrict__ AT) {
  const int bid = blockIdx.x;
  const int u = bid & 63, bh = bid >> 6, b = bh >> 4, h = bh & 15;
  const int tid = threadIdx.x, lane = tid & 63, wave = tid >> 6;
  const int l15 = lane & 15, l4 = lane >> 4;
  __shared__ float kc[64];
  __shared__ float dp[64][4];
  __shared__ float dinv[64];

  const size_t base = (size_t)bid * 4096;
  const u16* Qu = Q + base;
  if (tid < 64) kc[tid] = kcum[(size_t)bid * 64 + tid];
  __syncthreads();
  {
    int n = tid & 63, q = tid >> 6;
    const u16* qp = Qu + n * 64 + q * 16;
    float a = 0.f;
#pragma unroll
    for (int j = 0; j < 16; ++j) a += bf2f(qp[j]) * kc[q * 16 + j];
    dp[n][q] = a;
  }
  __syncthreads();
  if (tid < 64)
    dinv[tid] = 1.f / fmaxf(dp[tid][0] + dp[tid][1] + dp[tid][2] + dp[tid][3], 1e-3f);
  __syncthreads();

  f32x4 acc[4] = {};
  const u16* Cu = ctxc + base;
#pragma unroll
  for (int kk = 0; kk < 2; ++kk) {
    bf16x8 aq = *reinterpret_cast<const bf16x8*>(Qu + (wave * 16 + l15) * 64 + kk * 32 + l4 * 8);
#pragma unroll
    for (int ni = 0; ni < 4; ++ni) {
      bf16x8 bc = *reinterpret_cast<const bf16x8*>(Cu + (ni * 16 + l15) * 64 + kk * 32 + l4 * 8);
      acc[ni] = __builtin_amdgcn_mfma_f32_16x16x32_bf16(aq, bc, acc[ni], 0, 0, 0);
    }
  }
  const size_t orow = ((size_t)b * 4096 + u * 64 + wave * 16 + l4 * 4) * 1024 + h * 64;
#pragma unroll
  for (int i = 0; i < 4; ++i) {
    float di = dinv[wave * 16 + l4 * 4 + i];
#pragma unroll
    for (int ni = 0; ni < 4; ++ni)
      AT[orow + (size_t)i * 1024 + ni * 16 + l15] = f2bf(acc[ni][i] * di);
  }
}

// ----------------------------------------------------------------------------
extern "C" void kernel_launch(void* const* d_in, const int* in_sizes, int n_in,
                              void* d_out, int out_size, void* d_ws, size_t ws_size,
                              hipStream_t stream) {
  (void)in_sizes; (void)n_in; (void)out_size; (void)ws_size;
  const float* x      = (const float*)d_in[0];
  const float* qkv_w  = (const float*)d_in[1];
  const float* proj_w = (const float*)d_in[2];
  const float* proj_b = (const float*)d_in[3];
  float* out = (float*)d_out;

  char* ws = (char*)d_ws;
  u16* xb    = (u16*)(ws);
  u16* wq    = (u16*)(ws + 33554432);
  u16* wp    = (u16*)(ws + 39845888);
  u16* qkv   = (u16*)(ws + 41943040);
  u16* Qf    = (u16*)(ws + 142606336);
  u16* ctxb  = (u16*)(ws + 176160768);
  float* ksum = (float*)(ws + 209715200);
  u16* AT    = qkv;  // qkv region is dead after featuremap_ctx

  cvt_f32_to_bf16<<<dim3(16384), dim3(256), 0, stream>>>(x, xb, 16777216 / 4);
  cvt_f32_to_bf16<<<dim3(3072),  dim3(256), 0, stream>>>(qkv_w, wq, 3145728 / 4);
  cvt_f32_to_bf16<<<dim3(1024),  dim3(256), 0, stream>>>(proj_w, wp, 1048576 / 4);

  gemm_bt<true ><<<dim3(128 * 24), dim3(256), 0, stream>>>(xb, wq, nullptr, qkv,
                                                           16384, 3072, 1024);
  featuremap_ctx<<<dim3(4096), dim3(256), 0, stream>>>(qkv, Qf, ctxb, ksum);
  scanctx<<<dim3(256), dim3(256), 0, stream>>>(ctxb, ksum);
  apply<<<dim3(4096), dim3(256), 0, stream>>>(Qf, ctxb, ksum, AT);
  gemm_bt<false><<<dim3(128 * 8), dim3(256), 0, stream>>>(AT, wp, proj_b, out,
                                                          16384, 1024, 1024);
}

// Round 3
// 286.778 us; speedup vs baseline: 1.3939x; 1.0167x over previous
//
#include <hip/hip_runtime.h>
#include <stdint.h>

// ---------------------------------------------------------------------------
// Bucketed linear attention, round 2: 256x256 8-phase counted-vmcnt GEMM.
//   ws layout (<= 211 MB):
//     xb   bf16 x            33,554,432 B @ 0
//     wq   bf16 qkv_w         6,291,456 B @ 33554432
//     wp   bf16 proj_w        2,097,152 B @ 39845888
//     qkv  bf16 [16384][3072] 100,663,296 B @ 41943040   (reused as AT later)
//     Qf   bf16 [bkt][n][e]   33,554,432 B @ 142606336
//     ctxb bf16 [bkt][e][d]   33,554,432 B @ 176160768  (in-place excl scan)
//     ksum f32  [bkt][d]       1,048,576 B @ 209715200  (in-place excl scan)
// ---------------------------------------------------------------------------

typedef unsigned short u16;
typedef unsigned int u32;
typedef u16   u16x4  __attribute__((ext_vector_type(4)));
typedef u16   u16x8  __attribute__((ext_vector_type(8)));
typedef float f32x4  __attribute__((ext_vector_type(4)));
typedef float float4v __attribute__((ext_vector_type(4)));
typedef __bf16 bf16x8 __attribute__((ext_vector_type(8)));

__device__ __forceinline__ u16 f2bf(float f) {
  return __builtin_bit_cast(u16, (__bf16)f);
}
__device__ __forceinline__ float bf2f(u16 h) {
  return (float)__builtin_bit_cast(__bf16, h);
}

__device__ __forceinline__ void stage16(const u16* g, u16* l) {
  __builtin_amdgcn_global_load_lds(
      (const __attribute__((address_space(1))) u32*)g,
      (__attribute__((address_space(3))) u32*)l, 16, 0, 0);
}

// --------------------------- fp32 -> bf16 convert ---------------------------
__global__ __launch_bounds__(256) void cvt_f32_to_bf16(
    const float* __restrict__ in, u16* __restrict__ out, int n4) {
  int i = blockIdx.x * 256 + threadIdx.x;
  if (i >= n4) return;
  float4v v = reinterpret_cast<const float4v*>(in)[i];
  u16x4 o;
  o.x = f2bf(v.x); o.y = f2bf(v.y); o.z = f2bf(v.z); o.w = f2bf(v.w);
  reinterpret_cast<u16x4*>(out)[i] = o;
}

// ------------------ 256x256 8-phase NT bf16 MFMA GEMM -----------------------
// C[M][N] = A[M][K] @ B[N][K]^T (+bias when fp32 out). BK=64, 8 waves (2Mx4N),
// wave output 128x64. LDS [2 dbuf][2 khalf][256 rows][32 kcols] per operand.
// K-swizzle: physical 16B slot = logical ^ ((row>>1)&3) — applied on the
// global SOURCE address of global_load_lds (linear LDS dest) and on ds_read.
// Phase = (kk, mh): 16 MFMA each. Counted vmcnt(4) at phases 1,3 only.
template <bool BF16_OUT>
__global__ __launch_bounds__(512, 2) void gemm256(
    const u16* __restrict__ A,      // [M][K] bf16
    const u16* __restrict__ B,      // [N][K] bf16
    const float* __restrict__ bias, // [N] (when !BF16_OUT)
    void* __restrict__ Cv,
    int N, int K, int NT) {         // NT = K/64
  __shared__ u16 As[2][2][256][32];
  __shared__ u16 Bs[2][2][256][32];
  const int tid = threadIdx.x, lane = tid & 63, wave = tid >> 6;
  const int wm = wave >> 2, wn = wave & 3;
  const int l15 = lane & 15, l4 = lane >> 4;
  const int ntn = N >> 8;
  const int cpx = gridDim.x >> 3;
  const int bid = (blockIdx.x & 7) * cpx + (blockIdx.x >> 3);
  const int bm = bid / ntn, bn = bid % ntn;

  // staging constants: thread covers 16B at row (j*128 + tid>>2), phys slot
  // tid&3; fetch logical slot (tid&3)^((tid>>3)&3) so LDS dest stays linear.
  const int srow = tid >> 2;
  const int gsl8 = ((tid & 3) ^ ((tid >> 3) & 3)) * 8;
  const u16* Ag = A + (size_t)(bm * 256 + srow) * K + gsl8;
  const u16* Bg = B + (size_t)(bn * 256 + srow) * K + gsl8;
  const size_t rj = (size_t)128 * K;

  // ds_read: physical slot = l4 ^ ((row>>1)&3); only l15 affects (row>>1)&3.
  const int slotr = (l4 ^ ((l15 >> 1) & 3)) * 8;

  f32x4 acc[8][4] = {};
  bf16x8 a0, a1, a2, a3, b0, b1, b2, b3;

#define STG(P, buf, kh, kt)                                        \
  { const u16* g_ = P##g + (kt) + (kh) * 32;                       \
    stage16(g_,      &P##s[buf][kh][wave * 16][0]);                \
    stage16(g_ + rj, &P##s[buf][kh][128 + wave * 16][0]); }

#define LDA(kk, mh)                                                \
  { const u16* p_ = &As[cur][kk][wm * 128 + (mh) * 64 + l15][0] + slotr; \
    a0 = *(const bf16x8*)(p_);                                     \
    a1 = *(const bf16x8*)(p_ + 512);                               \
    a2 = *(const bf16x8*)(p_ + 1024);                              \
    a3 = *(const bf16x8*)(p_ + 1536); }

#define LDB(kk)                                                    \
  { const u16* p_ = &Bs[cur][kk][wn * 64 + l15][0] + slotr;        \
    b0 = *(const bf16x8*)(p_);                                     \
    b1 = *(const bf16x8*)(p_ + 512);                               \
    b2 = *(const bf16x8*)(p_ + 1024);                              \
    b3 = *(const bf16x8*)(p_ + 1536); }

#define MM(x, y, z) z = __builtin_amdgcn_mfma_f32_16x16x32_bf16(x, y, z, 0, 0, 0)
#define MFMA16(mb)                                                 \
  __builtin_amdgcn_s_setprio(1);                                   \
  MM(a0, b0, acc[(mb) + 0][0]); MM(a0, b1, acc[(mb) + 0][1]);      \
  MM(a0, b2, acc[(mb) + 0][2]); MM(a0, b3, acc[(mb) + 0][3]);      \
  MM(a1, b0, acc[(mb) + 1][0]); MM(a1, b1, acc[(mb) + 1][1]);      \
  MM(a1, b2, acc[(mb) + 1][2]); MM(a1, b3, acc[(mb) + 1][3]);      \
  MM(a2, b0, acc[(mb) + 2][0]); MM(a2, b1, acc[(mb) + 2][1]);      \
  MM(a2, b2, acc[(mb) + 2][2]); MM(a2, b3, acc[(mb) + 2][3]);      \
  MM(a3, b0, acc[(mb) + 3][0]); MM(a3, b1, acc[(mb) + 3][1]);      \
  MM(a3, b2, acc[(mb) + 3][2]); MM(a3, b3, acc[(mb) + 3][3]);      \
  __builtin_amdgcn_s_setprio(0);

#define BARF()                                                     \
  { asm volatile("" ::: "memory");                                 \
    __builtin_amdgcn_s_barrier();                                  \
    asm volatile("" ::: "memory"); }

  // prologue: stage tile 0 fully into buf 0, drain, barrier.
  STG(A, 0, 0, 0) STG(B, 0, 0, 0) STG(A, 0, 1, 0) STG(B, 0, 1, 0)
  asm volatile("s_waitcnt vmcnt(0)" ::: "memory");
  __builtin_amdgcn_s_barrier();
  asm volatile("" ::: "memory");

  for (int t = 0; t < NT; ++t) {
    const int cur = t & 1, nxt = cur ^ 1;
    const int ktn = (t + 1) << 6;
    const bool pre = (t + 1 < NT);
    // phase 0: kk=0, mh=0 — stage A-k0(t+1)
    LDB(0) LDA(0, 0)
    if (pre) STG(A, nxt, 0, ktn)
    BARF()
    MFMA16(0)
    BARF()
    // phase 1: kk=0, mh=1 — stage B-k0(t+1); vmcnt guards k1 reads
    LDA(0, 1)
    if (pre) STG(B, nxt, 0, ktn)
    BARF()
    MFMA16(4)
    if (pre) { asm volatile("s_waitcnt vmcnt(4)" ::: "memory"); }
    else     { asm volatile("s_waitcnt vmcnt(0)" ::: "memory"); }
    BARF()
    // phase 2: kk=1, mh=0 — stage A-k1(t+1)
    LDB(1) LDA(1, 0)
    if (pre) STG(A, nxt, 1, ktn)
    BARF()
    MFMA16(0)
    BARF()
    // phase 3: kk=1, mh=1 — stage B-k1(t+1); vmcnt guards next tile's k0
    LDA(1, 1)
    if (pre) STG(B, nxt, 1, ktn)
    BARF()
    MFMA16(4)
    if (pre) { asm volatile("s_waitcnt vmcnt(4)" ::: "memory"); }
    BARF()
  }
#undef STG
#undef LDA
#undef LDB
#undef MM
#undef MFMA16
#undef BARF

  // epilogue: D row=(lane>>4)*4+reg, col=lane&15
  const int row0 = bm * 256 + wm * 128 + l4 * 4;
  const int col0 = bn * 256 + wn * 64 + l15;
  if constexpr (BF16_OUT) {
    u16* C = (u16*)Cv;
#pragma unroll
    for (int mi = 0; mi < 8; ++mi)
#pragma unroll
      for (int i = 0; i < 4; ++i) {
        size_t r = (size_t)(row0 + mi * 16 + i) * N;
#pragma unroll
        for (int ni = 0; ni < 4; ++ni)
          C[r + col0 + ni * 16] = f2bf(acc[mi][ni][i]);
      }
  } else {
    float* C = (float*)Cv;
    float bv[4];
#pragma unroll
    for (int ni = 0; ni < 4; ++ni) bv[ni] = bias[col0 + ni * 16];
#pragma unroll
    for (int mi = 0; mi < 8; ++mi)
#pragma unroll
      for (int i = 0; i < 4; ++i) {
        size_t r = (size_t)(row0 + mi * 16 + i) * N;
#pragma unroll
        for (int ni = 0; ni < 4; ++ni)
          C[r + col0 + ni * 16] = acc[mi][ni][i] + bv[ni];
      }
  }
}

// ------------------ feature maps + per-bucket K^T V (fused) -----------------
__global__ __launch_bounds__(256) void featuremap_ctx(
    const u16* __restrict__ qkv,  // [16384][3072] bf16
    u16* __restrict__ Q, u16* __restrict__ ctxb, float* __restrict__ ksum) {
  const int bid = blockIdx.x;
  const int u = bid & 63;
  const int bh = bid >> 6;
  const int b = bh >> 4, h = bh & 15;
  const int tid = threadIdx.x, lane = tid & 63, wave = tid >> 6;
  const int l15 = lane & 15, l4 = lane >> 4;
  __shared__ float ts[64][65];
  __shared__ u16 KtL[64][72];
  __shared__ u16 VtL[64][72];
  __shared__ float dp[64][4];

  const size_t mrow  = (size_t)b * 4096 + u * 64;
  const size_t obase = (size_t)bid * 4096;

  // Q: softmax over e (64 lanes = e), each wave 16 rows
#pragma unroll 1
  for (int r = 0; r < 16; ++r) {
    int n = wave * 16 + r;
    float v = bf2f(qkv[(mrow + n) * 3072 + h * 64 + lane]);
    float mx = v;
#pragma unroll
    for (int o = 32; o; o >>= 1) mx = fmaxf(mx, __shfl_xor(mx, o));
    float ex = __expf(v - mx);
    float sm = ex;
#pragma unroll
    for (int o = 32; o; o >>= 1) sm += __shfl_xor(sm, o);
    Q[obase + n * 64 + lane] = f2bf(ex / sm * 0.125f);
  }

  // K: exp + transpose into KtL
  {
    int n = tid >> 2, c = tid & 3;
    const u16* kp = qkv + (mrow + n) * 3072 + 1024 + h * 64 + c * 16;
#pragma unroll
    for (int j = 0; j < 16; ++j) ts[n][c * 16 + j] = __expf(bf2f(kp[j]));
  }
  __syncthreads();
  {
    int d = tid >> 2, c = tid & 3;
    u16x8 o0, o1;
#pragma unroll
    for (int j = 0; j < 8; ++j) o0[j] = f2bf(ts[c * 16 + j][d]);
#pragma unroll
    for (int j = 0; j < 8; ++j) o1[j] = f2bf(ts[c * 16 + 8 + j][d]);
    *reinterpret_cast<u16x8*>(&KtL[d][c * 16])     = o0;
    *reinterpret_cast<u16x8*>(&KtL[d][c * 16 + 8]) = o1;
  }
  __syncthreads();
  {
    int d = tid & 63, q = tid >> 6;
    float a = 0.f;
#pragma unroll
    for (int j = 0; j < 16; ++j) a += bf2f(KtL[d][q * 16 + j]);
    dp[d][q] = a;
  }
  {
    int n = tid >> 2, c = tid & 3;
    const u16* vp = qkv + (mrow + n) * 3072 + 2048 + h * 64 + c * 16;
#pragma unroll
    for (int j = 0; j < 16; ++j) ts[n][c * 16 + j] = bf2f(vp[j]);
  }
  __syncthreads();
  if (tid < 64)
    ksum[obase / 64 + tid] = dp[tid][0] + dp[tid][1] + dp[tid][2] + dp[tid][3];
  {
    int e = tid >> 2, c = tid & 3;
    u16x8 o0, o1;
#pragma unroll
    for (int j = 0; j < 8; ++j) o0[j] = f2bf(ts[c * 16 + j][e]);
#pragma unroll
    for (int j = 0; j < 8; ++j) o1[j] = f2bf(ts[c * 16 + 8 + j][e]);
    *reinterpret_cast<u16x8*>(&VtL[e][c * 16])     = o0;
    *reinterpret_cast<u16x8*>(&VtL[e][c * 16 + 8]) = o1;
  }
  __syncthreads();

  f32x4 acc[4] = {};
#pragma unroll
  for (int kk = 0; kk < 2; ++kk) {
    bf16x8 av = *reinterpret_cast<const bf16x8*>(&VtL[wave * 16 + l15][kk * 32 + l4 * 8]);
#pragma unroll
    for (int ni = 0; ni < 4; ++ni) {
      bf16x8 bk = *reinterpret_cast<const bf16x8*>(&KtL[ni * 16 + l15][kk * 32 + l4 * 8]);
      acc[ni] = __builtin_amdgcn_mfma_f32_16x16x32_bf16(av, bk, acc[ni], 0, 0, 0);
    }
  }
  u16* cb = ctxb + obase;
#pragma unroll
  for (int ni = 0; ni < 4; ++ni)
#pragma unroll
    for (int i = 0; i < 4; ++i)
      cb[(wave * 16 + l4 * 4 + i) * 64 + ni * 16 + l15] = f2bf(acc[ni][i]);
}

// -------------------- in-place exclusive cumsum over u ----------------------
__global__ __launch_bounds__(256) void scanctx(
    u16* __restrict__ ctxb, float* __restrict__ ksum) {
  const int bh = blockIdx.x >> 2, c = blockIdx.x & 3;
  const int tid = threadIdx.x;
  u16* p = ctxb + (size_t)bh * 64 * 4096 + c * 1024 + tid * 4;
  float* kp = ksum + (size_t)bh * 64 * 64 + tid;
  const bool dok = (c == 0) && (tid < 64);

  float r0 = 0.f, r1 = 0.f, r2 = 0.f, r3 = 0.f, runk = 0.f;
#define LC(i) (*reinterpret_cast<const u16x4*>(p + (size_t)(i) * 4096))
#define LK(i) (dok ? kp[(size_t)(i) * 64] : 0.f)
  u16x4 c0 = LC(0), c1 = LC(1), c2 = LC(2), c3 = LC(3);
  float k0 = LK(0), k1 = LK(1), k2 = LK(2), k3 = LK(3);
  for (int u = 0; u < 64; u += 4) {
    const int i4 = u + 4 < 64 ? u + 4 : 63, i5 = u + 5 < 64 ? u + 5 : 63;
    const int i6 = u + 6 < 64 ? u + 6 : 63, i7 = u + 7 < 64 ? u + 7 : 63;
    u16x4 n0 = LC(i4), n1 = LC(i5), n2 = LC(i6), n3 = LC(i7);
    float m0 = LK(i4), m1 = LK(i5), m2 = LK(i6), m3 = LK(i7);
#define STEP(idx, cv, kv)                                                  \
    {                                                                      \
      u16x4 o;                                                             \
      o.x = f2bf(r0); o.y = f2bf(r1); o.z = f2bf(r2); o.w = f2bf(r3);      \
      *reinterpret_cast<u16x4*>(p + (size_t)(idx) * 4096) = o;             \
      if (dok) kp[(size_t)(idx) * 64] = runk;                              \
      r0 += bf2f(cv.x); r1 += bf2f(cv.y); r2 += bf2f(cv.z);                \
      r3 += bf2f(cv.w); runk += kv;                                        \
    }
    STEP(u, c0, k0) STEP(u + 1, c1, k1) STEP(u + 2, c2, k2) STEP(u + 3, c3, k3)
#undef STEP
    c0 = n0; c1 = n1; c2 = n2; c3 = n3;
    k0 = m0; k1 = m1; k2 = m2; k3 = m3;
  }
#undef LC
#undef LK
}

// ---------------- apply: attn = (q @ ctx_excl) * Dinv -> AT -----------------
__global__ __launch_bounds__(256) void apply(
    const u16* __restrict__ Q, const u16* __restrict__ ctxc,
    const float* __restrict__ kcum, u16* __restrict__ AT) {
  const int bid = blockIdx.x;
  const int u = bid & 63, bh = bid >> 6, b = bh >> 4, h = bh & 15;
  const int tid = threadIdx.x, lane = tid & 63, wave = tid >> 6;
  const int l15 = lane & 15, l4 = lane >> 4;
  __shared__ float kc[64];
  __shared__ float dp[64][4];
  __shared__ float dinv[64];

  const size_t base = (size_t)bid * 4096;
  const u16* Qu = Q + base;
  if (tid < 64) kc[tid] = kcum[(size_t)bid * 64 + tid];
  __syncthreads();
  {
    int n = tid & 63, q = tid >> 6;
    const u16* qp = Qu + n * 64 + q * 16;
    float a = 0.f;
#pragma unroll
    for (int j = 0; j < 16; ++j) a += bf2f(qp[j]) * kc[q * 16 + j];
    dp[n][q] = a;
  }
  __syncthreads();
  if (tid < 64)
    dinv[tid] = 1.f / fmaxf(dp[tid][0] + dp[tid][1] + dp[tid][2] + dp[tid][3], 1e-3f);
  __syncthreads();

  f32x4 acc[4] = {};
  const u16* Cu = ctxc + base;
#pragma unroll
  for (int kk = 0; kk < 2; ++kk) {
    bf16x8 aq = *reinterpret_cast<const bf16x8*>(Qu + (wave * 16 + l15) * 64 + kk * 32 + l4 * 8);
#pragma unroll
    for (int ni = 0; ni < 4; ++ni) {
      bf16x8 bc = *reinterpret_cast<const bf16x8*>(Cu + (ni * 16 + l15) * 64 + kk * 32 + l4 * 8);
      acc[ni] = __builtin_amdgcn_mfma_f32_16x16x32_bf16(aq, bc, acc[ni], 0, 0, 0);
    }
  }
  const size_t orow = ((size_t)b * 4096 + u * 64 + wave * 16 + l4 * 4) * 1024 + h * 64;
#pragma unroll
  for (int i = 0; i < 4; ++i) {
    float di = dinv[wave * 16 + l4 * 4 + i];
#pragma unroll
    for (int ni = 0; ni < 4; ++ni)
      AT[orow + (size_t)i * 1024 + ni * 16 + l15] = f2bf(acc[ni][i] * di);
  }
}

// ----------------------------------------------------------------------------
extern "C" void kernel_launch(void* const* d_in, const int* in_sizes, int n_in,
                              void* d_out, int out_size, void* d_ws, size_t ws_size,
                              hipStream_t stream) {
  (void)in_sizes; (void)n_in; (void)out_size; (void)ws_size;
  const float* x      = (const float*)d_in[0];
  const float* qkv_w  = (const float*)d_in[1];
  const float* proj_w = (const float*)d_in[2];
  const float* proj_b = (const float*)d_in[3];
  float* out = (float*)d_out;

  char* ws = (char*)d_ws;
  u16* xb    = (u16*)(ws);
  u16* wq    = (u16*)(ws + 33554432);
  u16* wp    = (u16*)(ws + 39845888);
  u16* qkv   = (u16*)(ws + 41943040);
  u16* Qf    = (u16*)(ws + 142606336);
  u16* ctxb  = (u16*)(ws + 176160768);
  float* ksum = (float*)(ws + 209715200);
  u16* AT    = qkv;  // qkv region is dead after featuremap_ctx

  cvt_f32_to_bf16<<<dim3(16384), dim3(256), 0, stream>>>(x, xb, 16777216 / 4);
  cvt_f32_to_bf16<<<dim3(3072),  dim3(256), 0, stream>>>(qkv_w, wq, 3145728 / 4);
  cvt_f32_to_bf16<<<dim3(1024),  dim3(256), 0, stream>>>(proj_w, wp, 1048576 / 4);

  gemm256<true ><<<dim3(64 * 12), dim3(512), 0, stream>>>(xb, wq, nullptr, qkv,
                                                          3072, 1024, 16);
  featuremap_ctx<<<dim3(4096), dim3(256), 0, stream>>>(qkv, Qf, ctxb, ksum);
  scanctx<<<dim3(256), dim3(256), 0, stream>>>(ctxb, ksum);
  apply<<<dim3(4096), dim3(256), 0, stream>>>(Qf, ctxb, ksum, AT);
  gemm256<false><<<dim3(64 * 4), dim3(512), 0, stream>>>(AT, wp, proj_b, out,
                                                         1024, 1024, 16);
}

// Round 4
// 286.563 us; speedup vs baseline: 1.3950x; 1.0008x over previous
//
#include <hip/hip_runtime.h>
#include <stdint.h>

// ---------------------------------------------------------------------------
// Bucketed linear attention, round 3: GEMM K-loop restructured — 2 barriers
// per K-tile (gate-per-k-half), 12-ds_read half-K register lookahead so
// phase-b MFMAs never lgkm-stall.
//   ws layout (<= 211 MB):
//     xb   bf16 x            33,554,432 B @ 0
//     wq   bf16 qkv_w         6,291,456 B @ 33554432
//     wp   bf16 proj_w        2,097,152 B @ 39845888
//     qkv  bf16 [16384][3072] 100,663,296 B @ 41943040   (reused as AT later)
//     Qf   bf16 [bkt][n][e]   33,554,432 B @ 142606336
//     ctxb bf16 [bkt][e][d]   33,554,432 B @ 176160768  (in-place excl scan)
//     ksum f32  [bkt][d]       1,048,576 B @ 209715200  (in-place excl scan)
// ---------------------------------------------------------------------------

typedef unsigned short u16;
typedef unsigned int u32;
typedef u16   u16x4  __attribute__((ext_vector_type(4)));
typedef u16   u16x8  __attribute__((ext_vector_type(8)));
typedef float f32x4  __attribute__((ext_vector_type(4)));
typedef float float4v __attribute__((ext_vector_type(4)));
typedef __bf16 bf16x8 __attribute__((ext_vector_type(8)));

__device__ __forceinline__ u16 f2bf(float f) {
  return __builtin_bit_cast(u16, (__bf16)f);
}
__device__ __forceinline__ float bf2f(u16 h) {
  return (float)__builtin_bit_cast(__bf16, h);
}

__device__ __forceinline__ void stage16(const u16* g, u16* l) {
  __builtin_amdgcn_global_load_lds(
      (const __attribute__((address_space(1))) u32*)g,
      (__attribute__((address_space(3))) u32*)l, 16, 0, 0);
}

// --------------------------- fp32 -> bf16 convert ---------------------------
__global__ __launch_bounds__(256) void cvt_f32_to_bf16(
    const float* __restrict__ in, u16* __restrict__ out, int n4) {
  int i = blockIdx.x * 256 + threadIdx.x;
  if (i >= n4) return;
  float4v v = reinterpret_cast<const float4v*>(in)[i];
  u16x4 o;
  o.x = f2bf(v.x); o.y = f2bf(v.y); o.z = f2bf(v.z); o.w = f2bf(v.w);
  reinterpret_cast<u16x4*>(out)[i] = o;
}

// ------------------ 256x256 NT bf16 MFMA GEMM (deep pipeline) ---------------
// C[M][N] = A[M][K] @ B[N][K]^T (+bias when fp32 out). BK=64, 8 waves (2Mx4N),
// wave output 128x64. LDS [2 dbuf][2 khalf][256 rows][32 kcols] per operand.
// K-swizzle: physical 16B slot = logical ^ ((row>>1)&3) — applied on the
// global SOURCE of global_load_lds (linear LDS dest) and on ds_read.
// Per K-tile: 2 gates only (vmcnt(4)+barrier per k-half). Each k-half loads
// B + BOTH A sub-tiles (12 ds_read_b128) up front; second MFMA16 runs on
// registers loaded a full phase earlier (no lgkm stall).
template <bool BF16_OUT>
__global__ __launch_bounds__(512, 2) void gemm256(
    const u16* __restrict__ A,      // [M][K] bf16
    const u16* __restrict__ B,      // [N][K] bf16
    const float* __restrict__ bias, // [N] (when !BF16_OUT)
    void* __restrict__ Cv,
    int N, int K, int NT) {         // NT = K/64
  __shared__ u16 As[2][2][256][32];
  __shared__ u16 Bs[2][2][256][32];
  const int tid = threadIdx.x, lane = tid & 63, wave = tid >> 6;
  const int wm = wave >> 2, wn = wave & 3;
  const int l15 = lane & 15, l4 = lane >> 4;
  const int ntn = N >> 8;
  const int cpx = gridDim.x >> 3;
  const int bid = (blockIdx.x & 7) * cpx + (blockIdx.x >> 3);
  const int bm = bid / ntn, bn = bid % ntn;

  // staging: thread covers 16B at row (j*128 + tid>>2), phys slot tid&3;
  // fetch logical slot (tid&3)^((tid>>3)&3) so LDS dest stays linear.
  const int srow = tid >> 2;
  const int gsl8 = ((tid & 3) ^ ((tid >> 3) & 3)) * 8;
  const u16* Ag = A + (size_t)(bm * 256 + srow) * K + gsl8;
  const u16* Bg = B + (size_t)(bn * 256 + srow) * K + gsl8;
  const size_t rj = (size_t)128 * K;

  // ds_read: physical slot = l4 ^ ((row>>1)&3); only l15 affects (row>>1)&3.
  const int slotr = (l4 ^ ((l15 >> 1) & 3)) * 8;

  f32x4 acc[8][4] = {};
  bf16x8 a0, a1, a2, a3, a4, a5, a6, a7, b0, b1, b2, b3;

#define STG(P, buf, kh, kt)                                        \
  { const u16* g_ = P##g + (kt) + (kh) * 32;                       \
    stage16(g_,      &P##s[buf][kh][wave * 16][0]);                \
    stage16(g_ + rj, &P##s[buf][kh][128 + wave * 16][0]); }

#define LDA(r0_, r1_, r2_, r3_, kk, mh)                                  \
  { const u16* p_ = &As[cur][kk][wm * 128 + (mh) * 64 + l15][0] + slotr; \
    r0_ = *(const bf16x8*)(p_);                                          \
    r1_ = *(const bf16x8*)(p_ + 512);                                    \
    r2_ = *(const bf16x8*)(p_ + 1024);                                   \
    r3_ = *(const bf16x8*)(p_ + 1536); }

#define LDB(kk)                                                    \
  { const u16* p_ = &Bs[cur][kk][wn * 64 + l15][0] + slotr;        \
    b0 = *(const bf16x8*)(p_);                                     \
    b1 = *(const bf16x8*)(p_ + 512);                               \
    b2 = *(const bf16x8*)(p_ + 1024);                              \
    b3 = *(const bf16x8*)(p_ + 1536); }

#define MM(x, y, z) z = __builtin_amdgcn_mfma_f32_16x16x32_bf16(x, y, z, 0, 0, 0)
#define MFMA16(mb, x0, x1, x2, x3)                                 \
  __builtin_amdgcn_s_setprio(1);                                   \
  MM(x0, b0, acc[(mb) + 0][0]); MM(x0, b1, acc[(mb) + 0][1]);      \
  MM(x0, b2, acc[(mb) + 0][2]); MM(x0, b3, acc[(mb) + 0][3]);      \
  MM(x1, b0, acc[(mb) + 1][0]); MM(x1, b1, acc[(mb) + 1][1]);      \
  MM(x1, b2, acc[(mb) + 1][2]); MM(x1, b3, acc[(mb) + 1][3]);      \
  MM(x2, b0, acc[(mb) + 2][0]); MM(x2, b1, acc[(mb) + 2][1]);      \
  MM(x2, b2, acc[(mb) + 2][2]); MM(x2, b3, acc[(mb) + 2][3]);      \
  MM(x3, b0, acc[(mb) + 3][0]); MM(x3, b1, acc[(mb) + 3][1]);      \
  MM(x3, b2, acc[(mb) + 3][2]); MM(x3, b3, acc[(mb) + 3][3]);      \
  __builtin_amdgcn_s_setprio(0);

#define BARF()                                                     \
  { asm volatile("" ::: "memory");                                 \
    __builtin_amdgcn_s_barrier();                                  \
    asm volatile("" ::: "memory"); }

  // prologue: stage tile 0 fully into buf 0, drain, barrier.
  STG(A, 0, 0, 0) STG(B, 0, 0, 0) STG(A, 0, 1, 0) STG(B, 0, 1, 0)
  asm volatile("s_waitcnt vmcnt(0)" ::: "memory");
  __builtin_amdgcn_s_barrier();
  asm volatile("" ::: "memory");

  for (int t = 0; t < NT; ++t) {
    const int cur = t & 1, nxt = cur ^ 1;
    const int ktn = (t + 1) << 6;
    const bool pre = (t + 1 < NT);
    // ---- k-half 0: 12 ds_reads up front; MFMA16(mh1) runs stall-free ----
    LDB(0)
    LDA(a0, a1, a2, a3, 0, 0)
    LDA(a4, a5, a6, a7, 0, 1)
    if (pre) STG(A, nxt, 0, ktn)
    MFMA16(0, a0, a1, a2, a3)
    if (pre) STG(B, nxt, 0, ktn)
    MFMA16(4, a4, a5, a6, a7)
    // gate G2: all waves' k1 staging (prev iter) landed -> k1 readable
    if (pre) { asm volatile("s_waitcnt vmcnt(4)" ::: "memory"); }
    else     { asm volatile("s_waitcnt vmcnt(0)" ::: "memory"); }
    BARF()
    // ---- k-half 1 ----
    LDB(1)
    LDA(a0, a1, a2, a3, 1, 0)
    LDA(a4, a5, a6, a7, 1, 1)
    if (pre) STG(A, nxt, 1, ktn)
    MFMA16(0, a0, a1, a2, a3)
    if (pre) STG(B, nxt, 1, ktn)
    MFMA16(4, a4, a5, a6, a7)
    // gate G1: all waves' k0 staging (this iter) landed -> next tile k0 ok
    if (pre) { asm volatile("s_waitcnt vmcnt(4)" ::: "memory"); }
    BARF()
  }
#undef STG
#undef LDA
#undef LDB
#undef MM
#undef MFMA16
#undef BARF

  // epilogue: D row=(lane>>4)*4+reg, col=lane&15
  const int row0 = bm * 256 + wm * 128 + l4 * 4;
  const int col0 = bn * 256 + wn * 64 + l15;
  if constexpr (BF16_OUT) {
    u16* C = (u16*)Cv;
#pragma unroll
    for (int mi = 0; mi < 8; ++mi)
#pragma unroll
      for (int i = 0; i < 4; ++i) {
        size_t r = (size_t)(row0 + mi * 16 + i) * N;
#pragma unroll
        for (int ni = 0; ni < 4; ++ni)
          C[r + col0 + ni * 16] = f2bf(acc[mi][ni][i]);
      }
  } else {
    float* C = (float*)Cv;
    float bv[4];
#pragma unroll
    for (int ni = 0; ni < 4; ++ni) bv[ni] = bias[col0 + ni * 16];
#pragma unroll
    for (int mi = 0; mi < 8; ++mi)
#pragma unroll
      for (int i = 0; i < 4; ++i) {
        size_t r = (size_t)(row0 + mi * 16 + i) * N;
#pragma unroll
        for (int ni = 0; ni < 4; ++ni)
          C[r + col0 + ni * 16] = acc[mi][ni][i] + bv[ni];
      }
  }
}

// ------------------ feature maps + per-bucket K^T V (fused) -----------------
__global__ __launch_bounds__(256) void featuremap_ctx(
    const u16* __restrict__ qkv,  // [16384][3072] bf16
    u16* __restrict__ Q, u16* __restrict__ ctxb, float* __restrict__ ksum) {
  const int bid = blockIdx.x;
  const int u = bid & 63;
  const int bh = bid >> 6;
  const int b = bh >> 4, h = bh & 15;
  const int tid = threadIdx.x, lane = tid & 63, wave = tid >> 6;
  const int l15 = lane & 15, l4 = lane >> 4;
  __shared__ float ts[64][65];
  __shared__ u16 KtL[64][72];
  __shared__ u16 VtL[64][72];
  __shared__ float dp[64][4];

  const size_t mrow  = (size_t)b * 4096 + u * 64;
  const size_t obase = (size_t)bid * 4096;

  // Q: softmax over e (64 lanes = e), each wave 16 rows
#pragma unroll 1
  for (int r = 0; r < 16; ++r) {
    int n = wave * 16 + r;
    float v = bf2f(qkv[(mrow + n) * 3072 + h * 64 + lane]);
    float mx = v;
#pragma unroll
    for (int o = 32; o; o >>= 1) mx = fmaxf(mx, __shfl_xor(mx, o));
    float ex = __expf(v - mx);
    float sm = ex;
#pragma unroll
    for (int o = 32; o; o >>= 1) sm += __shfl_xor(sm, o);
    Q[obase + n * 64 + lane] = f2bf(ex / sm * 0.125f);
  }

  // K: exp + transpose into KtL
  {
    int n = tid >> 2, c = tid & 3;
    const u16* kp = qkv + (mrow + n) * 3072 + 1024 + h * 64 + c * 16;
#pragma unroll
    for (int j = 0; j < 16; ++j) ts[n][c * 16 + j] = __expf(bf2f(kp[j]));
  }
  __syncthreads();
  {
    int d = tid >> 2, c = tid & 3;
    u16x8 o0, o1;
#pragma unroll
    for (int j = 0; j < 8; ++j) o0[j] = f2bf(ts[c * 16 + j][d]);
#pragma unroll
    for (int j = 0; j < 8; ++j) o1[j] = f2bf(ts[c * 16 + 8 + j][d]);
    *reinterpret_cast<u16x8*>(&KtL[d][c * 16])     = o0;
    *reinterpret_cast<u16x8*>(&KtL[d][c * 16 + 8]) = o1;
  }
  __syncthreads();
  {
    int d = tid & 63, q = tid >> 6;
    float a = 0.f;
#pragma unroll
    for (int j = 0; j < 16; ++j) a += bf2f(KtL[d][q * 16 + j]);
    dp[d][q] = a;
  }
  {
    int n = tid >> 2, c = tid & 3;
    const u16* vp = qkv + (mrow + n) * 3072 + 2048 + h * 64 + c * 16;
#pragma unroll
    for (int j = 0; j < 16; ++j) ts[n][c * 16 + j] = bf2f(vp[j]);
  }
  __syncthreads();
  if (tid < 64)
    ksum[obase / 64 + tid] = dp[tid][0] + dp[tid][1] + dp[tid][2] + dp[tid][3];
  {
    int e = tid >> 2, c = tid & 3;
    u16x8 o0, o1;
#pragma unroll
    for (int j = 0; j < 8; ++j) o0[j] = f2bf(ts[c * 16 + j][e]);
#pragma unroll
    for (int j = 0; j < 8; ++j) o1[j] = f2bf(ts[c * 16 + 8 + j][e]);
    *reinterpret_cast<u16x8*>(&VtL[e][c * 16])     = o0;
    *reinterpret_cast<u16x8*>(&VtL[e][c * 16 + 8]) = o1;
  }
  __syncthreads();

  f32x4 acc[4] = {};
#pragma unroll
  for (int kk = 0; kk < 2; ++kk) {
    bf16x8 av = *reinterpret_cast<const bf16x8*>(&VtL[wave * 16 + l15][kk * 32 + l4 * 8]);
#pragma unroll
    for (int ni = 0; ni < 4; ++ni) {
      bf16x8 bk = *reinterpret_cast<const bf16x8*>(&KtL[ni * 16 + l15][kk * 32 + l4 * 8]);
      acc[ni] = __builtin_amdgcn_mfma_f32_16x16x32_bf16(av, bk, acc[ni], 0, 0, 0);
    }
  }
  u16* cb = ctxb + obase;
#pragma unroll
  for (int ni = 0; ni < 4; ++ni)
#pragma unroll
    for (int i = 0; i < 4; ++i)
      cb[(wave * 16 + l4 * 4 + i) * 64 + ni * 16 + l15] = f2bf(acc[ni][i]);
}

// -------------------- in-place exclusive cumsum over u ----------------------
__global__ __launch_bounds__(256) void scanctx(
    u16* __restrict__ ctxb, float* __restrict__ ksum) {
  const int bh = blockIdx.x >> 2, c = blockIdx.x & 3;
  const int tid = threadIdx.x;
  u16* p = ctxb + (size_t)bh * 64 * 4096 + c * 1024 + tid * 4;
  float* kp = ksum + (size_t)bh * 64 * 64 + tid;
  const bool dok = (c == 0) && (tid < 64);

  float r0 = 0.f, r1 = 0.f, r2 = 0.f, r3 = 0.f, runk = 0.f;
#define LC(i) (*reinterpret_cast<const u16x4*>(p + (size_t)(i) * 4096))
#define LK(i) (dok ? kp[(size_t)(i) * 64] : 0.f)
  u16x4 c0 = LC(0), c1 = LC(1), c2 = LC(2), c3 = LC(3);
  float k0 = LK(0), k1 = LK(1), k2 = LK(2), k3 = LK(3);
  for (int u = 0; u < 64; u += 4) {
    const int i4 = u + 4 < 64 ? u + 4 : 63, i5 = u + 5 < 64 ? u + 5 : 63;
    const int i6 = u + 6 < 64 ? u + 6 : 63, i7 = u + 7 < 64 ? u + 7 : 63;
    u16x4 n0 = LC(i4), n1 = LC(i5), n2 = LC(i6), n3 = LC(i7);
    float m0 = LK(i4), m1 = LK(i5), m2 = LK(i6), m3 = LK(i7);
#define STEP(idx, cv, kv)                                                  \
    {                                                                      \
      u16x4 o;                                                             \
      o.x = f2bf(r0); o.y = f2bf(r1); o.z = f2bf(r2); o.w = f2bf(r3);      \
      *reinterpret_cast<u16x4*>(p + (size_t)(idx) * 4096) = o;             \
      if (dok) kp[(size_t)(idx) * 64] = runk;                              \
      r0 += bf2f(cv.x); r1 += bf2f(cv.y); r2 += bf2f(cv.z);                \
      r3 += bf2f(cv.w); runk += kv;                                        \
    }
    STEP(u, c0, k0) STEP(u + 1, c1, k1) STEP(u + 2, c2, k2) STEP(u + 3, c3, k3)
#undef STEP
    c0 = n0; c1 = n1; c2 = n2; c3 = n3;
    k0 = m0; k1 = m1; k2 = m2; k3 = m3;
  }
#undef LC
#undef LK
}

// ---------------- apply: attn = (q @ ctx_excl) * Dinv -> AT -----------------
__global__ __launch_bounds__(256) void apply(
    const u16* __restrict__ Q, const u16* __restrict__ ctxc,
    const float* __restrict__ kcum, u16* __restrict__ AT) {
  const int bid = blockIdx.x;
  const int u = bid & 63, bh = bid >> 6, b = bh >> 4, h = bh & 15;
  const int tid = threadIdx.x, lane = tid & 63, wave = tid >> 6;
  const int l15 = lane & 15, l4 = lane >> 4;
  __shared__ float kc[64];
  __shared__ float dp[64][4];
  __shared__ float dinv[64];

  const size_t base = (size_t)bid * 4096;
  const u16* Qu = Q + base;
  if (tid < 64) kc[tid] = kcum[(size_t)bid * 64 + tid];
  __syncthreads();
  {
    int n = tid & 63, q = tid >> 6;
    const u16* qp = Qu + n * 64 + q * 16;
    float a = 0.f;
#pragma unroll
    for (int j = 0; j < 16; ++j) a += bf2f(qp[j]) * kc[q * 16 + j];
    dp[n][q] = a;
  }
  __syncthreads();
  if (tid < 64)
    dinv[tid] = 1.f / fmaxf(dp[tid][0] + dp[tid][1] + dp[tid][2] + dp[tid][3], 1e-3f);
  __syncthreads();

  f32x4 acc[4] = {};
  const u16* Cu = ctxc + base;
#pragma unroll
  for (int kk = 0; kk < 2; ++kk) {
    bf16x8 aq = *reinterpret_cast<const bf16x8*>(Qu + (wave * 16 + l15) * 64 + kk * 32 + l4 * 8);
#pragma unroll
    for (int ni = 0; ni < 4; ++ni) {
      bf16x8 bc = *reinterpret_cast<const bf16x8*>(Cu + (ni * 16 + l15) * 64 + kk * 32 + l4 * 8);
      acc[ni] = __builtin_amdgcn_mfma_f32_16x16x32_bf16(aq, bc, acc[ni], 0, 0, 0);
    }
  }
  const size_t orow = ((size_t)b * 4096 + u * 64 + wave * 16 + l4 * 4) * 1024 + h * 64;
#pragma unroll
  for (int i = 0; i < 4; ++i) {
    float di = dinv[wave * 16 + l4 * 4 + i];
#pragma unroll
    for (int ni = 0; ni < 4; ++ni)
      AT[orow + (size_t)i * 1024 + ni * 16 + l15] = f2bf(acc[ni][i] * di);
  }
}

// ----------------------------------------------------------------------------
extern "C" void kernel_launch(void* const* d_in, const int* in_sizes, int n_in,
                              void* d_out, int out_size, void* d_ws, size_t ws_size,
                              hipStream_t stream) {
  (void)in_sizes; (void)n_in; (void)out_size; (void)ws_size;
  const float* x      = (const float*)d_in[0];
  const float* qkv_w  = (const float*)d_in[1];
  const float* proj_w = (const float*)d_in[2];
  const float* proj_b = (const float*)d_in[3];
  float* out = (float*)d_out;

  char* ws = (char*)d_ws;
  u16* xb    = (u16*)(ws);
  u16* wq    = (u16*)(ws + 33554432);
  u16* wp    = (u16*)(ws + 39845888);
  u16* qkv   = (u16*)(ws + 41943040);
  u16* Qf    = (u16*)(ws + 142606336);
  u16* ctxb  = (u16*)(ws + 176160768);
  float* ksum = (float*)(ws + 209715200);
  u16* AT    = qkv;  // qkv region is dead after featuremap_ctx

  cvt_f32_to_bf16<<<dim3(16384), dim3(256), 0, stream>>>(x, xb, 16777216 / 4);
  cvt_f32_to_bf16<<<dim3(3072),  dim3(256), 0, stream>>>(qkv_w, wq, 3145728 / 4);
  cvt_f32_to_bf16<<<dim3(1024),  dim3(256), 0, stream>>>(proj_w, wp, 1048576 / 4);

  gemm256<true ><<<dim3(64 * 12), dim3(512), 0, stream>>>(xb, wq, nullptr, qkv,
                                                          3072, 1024, 16);
  featuremap_ctx<<<dim3(4096), dim3(256), 0, stream>>>(qkv, Qf, ctxb, ksum);
  scanctx<<<dim3(256), dim3(256), 0, stream>>>(ctxb, ksum);
  apply<<<dim3(4096), dim3(256), 0, stream>>>(Qf, ctxb, ksum, AT);
  gemm256<false><<<dim3(64 * 4), dim3(512), 0, stream>>>(AT, wp, proj_b, out,
                                                         1024, 1024, 16);
}